// Round 3
// baseline (529.285 us; speedup 1.0000x reference)
//
#include <hip/hip_runtime.h>
#include <hip/hip_bf16.h>

// Problem: B=4, L=2048, C=1024, H=16, D=64, M=B*L=8192. I/O f32.
// Internal: bf16 MFMA, f32 accumulate. Verified absmax 9.8e-4 vs 4.04e-3 thr (R2).

typedef __attribute__((ext_vector_type(8))) short bf16x8;
typedef __attribute__((ext_vector_type(4))) float f32x4;

#define MAXLOG 4.60517018598809f   // ln(100)
#define LOG2E  1.4426950408889634f

__device__ __forceinline__ float bf2f(unsigned short u) {
    union { unsigned int i; float f; } v; v.i = ((unsigned int)u) << 16; return v.f;
}
__device__ __forceinline__ unsigned short f2bf(float f) {
    union { float f; unsigned int i; } v; v.f = f;
    unsigned int x = v.i;
    return (unsigned short)((x + 0x7FFFu + ((x >> 16) & 1u)) >> 16);  // RNE
}
__device__ __forceinline__ bf16x8 pack8(const float* __restrict__ p) {
    float4 a = *(const float4*)p;
    float4 b = *(const float4*)(p + 4);
    bf16x8 r;
    r[0] = (short)f2bf(a.x); r[1] = (short)f2bf(a.y);
    r[2] = (short)f2bf(a.z); r[3] = (short)f2bf(a.w);
    r[4] = (short)f2bf(b.x); r[5] = (short)f2bf(b.y);
    r[6] = (short)f2bf(b.z); r[7] = (short)f2bf(b.w);
    return r;
}
// async global->LDS, 16B per lane; lds dest = wave-uniform base + lane*16
__device__ __forceinline__ void gload_lds16(const void* g, void* l) {
    __builtin_amdgcn_global_load_lds((const __attribute__((address_space(1))) void*)g,
                                     (__attribute__((address_space(3))) void*)l, 16, 0, 0);
}

// ------------------------------------------------------------ f32 -> bf16 cast
__global__ __launch_bounds__(256) void k_cast_bf16(const float* __restrict__ src,
                                                   unsigned short* __restrict__ dst, int n8) {
    int i = blockIdx.x * 256 + threadIdx.x;
    if (i < n8) *(bf16x8*)&dst[(long)i * 8] = pack8(&src[(long)i * 8]);
}

// ---------------------------------------------------------------- bias build
__global__ void k_build_bias(const float* __restrict__ qb, const float* __restrict__ vb,
                             float* __restrict__ bias3) {
    int i = blockIdx.x * 256 + threadIdx.x;
    if (i < 3072) {
        float v = 0.0f;
        if (i < 1024) v = qb[i];
        else if (i >= 2048) v = vb[i - 2048];
        bias3[i] = v;
    }
}

// --------------------------------------- GEMM, B^T input, global_load_lds staging
// C[m][n] = sum_k A[m][k]*Bm[n][k] + bias[n]; A bf16 [M,K]; Bm bf16 or f32 [N,K]
template<bool B_F32, bool OUT_F32>
__global__ __launch_bounds__(256) void k_gemm_lds(
    const unsigned short* __restrict__ A, const void* __restrict__ Bp,
    const float* __restrict__ bias, void* __restrict__ Cp, int N, int K)
{
    __shared__ unsigned short As[128 * 32];
    __shared__ unsigned short Bs[128 * 32];
    const int t = threadIdx.x, wave = t >> 6, lane = t & 63;
    const int quad = lane >> 4, l16 = lane & 15;
    const int bm = blockIdx.x * 128, bn = blockIdx.y * 128;
    const int wr = (wave >> 1) * 64, wc = (wave & 1) * 64;
    f32x4 acc[4][4] = {};

    const int srow = lane >> 2;        // 0..15 within 16-row chunk
    const int scol = (lane & 3) * 8;   // bf16 elems
    const int c0 = wave * 2, c1 = wave * 2 + 1;   // chunk ids 0..7
    const long ga0 = (long)(bm + c0 * 16 + srow) * K + scol;
    const long ga1 = (long)(bm + c1 * 16 + srow) * K + scol;
    const int sr = t >> 2, sc2 = (t & 3) * 8;     // f32-B staging map
    const float* Bf = (const float*)Bp;
    const unsigned short* Bh = (const unsigned short*)Bp;
    const long gb0 = B_F32 ? ((long)(bn + sr) * K + sc2)      : ((long)(bn + c0 * 16 + srow) * K + scol);
    const long gb1 = B_F32 ? ((long)(bn + sr + 64) * K + sc2) : ((long)(bn + c1 * 16 + srow) * K + scol);

    for (int kt = 0; kt < K; kt += 32) {
        __syncthreads();
        gload_lds16(&A[ga0 + kt], &As[c0 * 512]);
        gload_lds16(&A[ga1 + kt], &As[c1 * 512]);
        if (B_F32) {
            *(bf16x8*)&Bs[sr * 32 + sc2]        = pack8(&Bf[gb0 + kt]);
            *(bf16x8*)&Bs[(sr + 64) * 32 + sc2] = pack8(&Bf[gb1 + kt]);
        } else {
            gload_lds16(&Bh[gb0 + kt], &Bs[c0 * 512]);
            gload_lds16(&Bh[gb1 + kt], &Bs[c1 * 512]);
        }
        __syncthreads();
        bf16x8 af[4], bfr[4];
        for (int i = 0; i < 4; ++i)
            af[i] = *(const bf16x8*)&As[(wr + i * 16 + l16) * 32 + quad * 8];
        for (int j = 0; j < 4; ++j)
            bfr[j] = *(const bf16x8*)&Bs[(wc + j * 16 + l16) * 32 + quad * 8];
        for (int i = 0; i < 4; ++i)
            for (int j = 0; j < 4; ++j)
                acc[i][j] = __builtin_amdgcn_mfma_f32_16x16x32_bf16(af[i], bfr[j], acc[i][j], 0, 0, 0);
    }
    for (int j = 0; j < 4; ++j) {
        int gn = bn + wc + j * 16 + l16;
        float bv = bias[gn];
        for (int i = 0; i < 4; ++i) {
            int gm0 = bm + wr + i * 16 + quad * 4;
            for (int r = 0; r < 4; ++r) {
                float val = acc[i][j][r] + bv;
                if (OUT_F32) ((float*)Cp)[(long)(gm0 + r) * N + gn] = val;
                else ((unsigned short*)Cp)[(long)(gm0 + r) * N + gn] = f2bf(val);
            }
        }
    }
}

// --------------------------------------------- k L2-normalize + head reshape
__global__ __launch_bounds__(256) void k_norm_k(
    const unsigned short* __restrict__ qkv, unsigned short* __restrict__ kb)
{
    const int wid = blockIdx.x * 4 + (threadIdx.x >> 6);
    const int lane = threadIdx.x & 63;
    const int h = wid & 15, m = wid >> 4;
    const int b = m >> 11, l = m & 2047;
    float kv = bf2f(qkv[(long)m * 3072 + 1024 + h * 64 + lane]);
    float sk = kv * kv;
    for (int s = 32; s; s >>= 1) sk += __shfl_xor(sk, s, 64);
    float kn = kv / fmaxf(sqrtf(sk), 1e-12f);
    kb[((long)(b * 16 + h) * 2048 + l) * 64 + lane] = f2bf(kn);
}

// --------------------------------------------------- v transpose to [B,H,D,L]
__global__ __launch_bounds__(256) void k_vtrans(
    const unsigned short* __restrict__ qkv, unsigned short* __restrict__ vT)
{
    __shared__ unsigned short Vsh[64 * 72];
    const int t = threadIdx.x;
    const int bh = blockIdx.y, l0 = blockIdx.x * 64;
    const int h = bh & 15, b = bh >> 4;
    const int ll = t >> 2, d0 = (t & 3) * 16;
    long src = (long)(b * 2048 + l0 + ll) * 3072 + 2048 + h * 64 + d0;
    *(bf16x8*)&Vsh[ll * 72 + d0]     = *(const bf16x8*)&qkv[src];
    *(bf16x8*)&Vsh[ll * 72 + d0 + 8] = *(const bf16x8*)&qkv[src + 8];
    __syncthreads();
    const int d = t >> 2, ls = (t & 3) * 16;
    unsigned short tmp[16];
    for (int j = 0; j < 16; ++j) tmp[j] = Vsh[(ls + j) * 72 + d];
    long dst = (long)(bh * 64 + d) * 2048 + l0 + ls;
    *(bf16x8*)&vT[dst]     = *(bf16x8*)&tmp[0];
    *(bf16x8*)&vT[dst + 8] = *(bf16x8*)&tmp[8];
}

// ------------------------------------------------------------ flash attention
// 128 q-rows/block, 32/wave (2 groups of 16). Fused q-norm. Constant shift
// c=scale (|q|=scale, |k|=1 => |S|<=scale). P trunc-packed; l from same P.
__global__ __launch_bounds__(256) void k_attn(
    const unsigned short* __restrict__ qkv, const unsigned short* __restrict__ kb,
    const unsigned short* __restrict__ vT, const float* __restrict__ sml,
    unsigned short* __restrict__ attn)
{
    __shared__ unsigned short Ks[64 * 72];
    __shared__ unsigned short Vs[64 * 72];
    __shared__ unsigned short Ps[4 * 32 * 72];
    const int t = threadIdx.x, wave = t >> 6, lane = t & 63;
    const int quad = lane >> 4, l16 = lane & 15;
    const int bh = blockIdx.y, h = bh & 15, b = bh >> 4;
    const int q0 = blockIdx.x * 128;
    const float scale = __expf(fminf(sml[h], MAXLOG));
    const float c2 = scale * LOG2E;

    // fused q load + L2-normalize + scale (A-frag layout: row=l16, k=quad*8+j)
    bf16x8 aq[2][2];
    for (int g = 0; g < 2; ++g) {
        int lrow = q0 + wave * 32 + g * 16 + l16;
        long base = (long)(b * 2048 + lrow) * 3072 + h * 64 + quad * 8;
        aq[g][0] = *(const bf16x8*)&qkv[base];
        aq[g][1] = *(const bf16x8*)&qkv[base + 32];
        float e[16]; float ss = 0.f;
        for (int j = 0; j < 8; ++j) { e[j]     = bf2f((unsigned short)aq[g][0][j]); ss += e[j] * e[j]; }
        for (int j = 0; j < 8; ++j) { e[8 + j] = bf2f((unsigned short)aq[g][1][j]); ss += e[8 + j] * e[8 + j]; }
        ss += __shfl_xor(ss, 16, 64);
        ss += __shfl_xor(ss, 32, 64);
        float rs = scale / fmaxf(sqrtf(ss), 1e-12f);
        for (int j = 0; j < 8; ++j) aq[g][0][j] = (short)f2bf(e[j] * rs);
        for (int j = 0; j < 8; ++j) aq[g][1][j] = (short)f2bf(e[8 + j] * rs);
    }

    f32x4 o[2][4] = {};
    f32x4 lacc[2] = {};
    bf16x8 ones; for (int i = 0; i < 8; ++i) ones[i] = (short)0x3F80;

    unsigned short* Pw = &Ps[wave * 32 * 72];
    const int rot = ((l16 >> 2) & 3) << 4;   // XOR column swizzle (bank-conflict-free P writes)
    const int sr = t >> 2, sc = (t & 3) * 16;

    for (int kt = 0; kt < 2048; kt += 64) {
        __syncthreads();
        long ksrc = ((long)bh * 2048 + kt + sr) * 64 + sc;
        *(bf16x8*)&Ks[sr * 72 + sc]     = *(const bf16x8*)&kb[ksrc];
        *(bf16x8*)&Ks[sr * 72 + sc + 8] = *(const bf16x8*)&kb[ksrc + 8];
        long vsrc = ((long)bh * 64 + sr) * 2048 + kt + sc;
        *(bf16x8*)&Vs[sr * 72 + sc]     = *(const bf16x8*)&vT[vsrc];
        *(bf16x8*)&Vs[sr * 72 + sc + 8] = *(const bf16x8*)&vT[vsrc + 8];
        __syncthreads();

        bf16x8 bk[4][2];
        for (int nt = 0; nt < 4; ++nt) {
            bk[nt][0] = *(const bf16x8*)&Ks[(nt * 16 + l16) * 72 + quad * 8];
            bk[nt][1] = *(const bf16x8*)&Ks[(nt * 16 + l16) * 72 + quad * 8 + 32];
        }
        for (int g = 0; g < 2; ++g) {
            f32x4 s[4] = {};
            for (int nt = 0; nt < 4; ++nt) {
                s[nt] = __builtin_amdgcn_mfma_f32_16x16x32_bf16(aq[g][0], bk[nt][0], s[nt], 0, 0, 0);
                s[nt] = __builtin_amdgcn_mfma_f32_16x16x32_bf16(aq[g][1], bk[nt][1], s[nt], 0, 0, 0);
            }
            // P = exp2(s*log2e - c2); write swizzled col' = ((nt^quad)<<4)+l16
            for (int nt = 0; nt < 4; ++nt) {
                int colb = ((nt ^ quad) << 4) + l16;
                for (int r = 0; r < 4; ++r) {
                    union { float f; unsigned int u; } cv;
                    cv.f = __builtin_amdgcn_exp2f(s[nt][r] * LOG2E - c2);
                    Pw[(g * 16 + quad * 4 + r) * 72 + colb] = (unsigned short)(cv.u >> 16);
                }
            }
        }
        bf16x8 ap[2][2];
        for (int g = 0; g < 2; ++g) {
            ap[g][0] = *(const bf16x8*)&Pw[(g * 16 + l16) * 72 + ((quad * 8) ^ rot)];
            ap[g][1] = *(const bf16x8*)&Pw[(g * 16 + l16) * 72 + ((quad * 8 + 32) ^ rot)];
        }
        for (int nt = 0; nt < 4; ++nt) {
            bf16x8 bv0 = *(const bf16x8*)&Vs[(nt * 16 + l16) * 72 + quad * 8];
            bf16x8 bv1 = *(const bf16x8*)&Vs[(nt * 16 + l16) * 72 + quad * 8 + 32];
            o[0][nt] = __builtin_amdgcn_mfma_f32_16x16x32_bf16(ap[0][0], bv0, o[0][nt], 0, 0, 0);
            o[0][nt] = __builtin_amdgcn_mfma_f32_16x16x32_bf16(ap[0][1], bv1, o[0][nt], 0, 0, 0);
            o[1][nt] = __builtin_amdgcn_mfma_f32_16x16x32_bf16(ap[1][0], bv0, o[1][nt], 0, 0, 0);
            o[1][nt] = __builtin_amdgcn_mfma_f32_16x16x32_bf16(ap[1][1], bv1, o[1][nt], 0, 0, 0);
        }
        lacc[0] = __builtin_amdgcn_mfma_f32_16x16x32_bf16(ap[0][0], ones, lacc[0], 0, 0, 0);
        lacc[0] = __builtin_amdgcn_mfma_f32_16x16x32_bf16(ap[0][1], ones, lacc[0], 0, 0, 0);
        lacc[1] = __builtin_amdgcn_mfma_f32_16x16x32_bf16(ap[1][0], ones, lacc[1], 0, 0, 0);
        lacc[1] = __builtin_amdgcn_mfma_f32_16x16x32_bf16(ap[1][1], ones, lacc[1], 0, 0, 0);
    }

    for (int g = 0; g < 2; ++g)
        for (int r = 0; r < 4; ++r) {
            float inv = 1.0f / lacc[g][r];
            int lrow = q0 + wave * 32 + g * 16 + quad * 4 + r;
            long dst = (long)(b * 2048 + lrow) * 1024 + h * 64;
            for (int nt = 0; nt < 4; ++nt)
                attn[dst + nt * 16 + l16] = f2bf(o[g][nt][r] * inv);
        }
}

// ---------------------------------------------------------------------------
extern "C" void kernel_launch(void* const* d_in, const int* in_sizes, int n_in,
                              void* d_out, int out_size, void* d_ws, size_t ws_size,
                              hipStream_t stream) {
    const float* x    = (const float*)d_in[0];
    const float* Wqkv = (const float*)d_in[1];
    const float* qbia = (const float*)d_in[2];
    const float* vbia = (const float*)d_in[3];
    const float* sml  = (const float*)d_in[4];
    const float* Wp   = (const float*)d_in[5];
    const float* bp   = (const float*)d_in[6];

    char* ws = (char*)d_ws;
    // Lifetime-overlapped layout (peak 100.68 MB, same as R2):
    unsigned short* qkv   = (unsigned short*)ws;                    // [0, 50.33MB)
    unsigned short* kbuf  = (unsigned short*)(ws + 50331648);       // 16.78MB; hosts Wqkvb first
    unsigned short* Wqkvb = kbuf;                                   // dead before k_norm_k writes kbuf
    unsigned short* vT    = (unsigned short*)(ws + 67108864);       // 16.78MB; hosts xb first
    unsigned short* xb    = vT;                                     // dead before k_vtrans writes vT
    unsigned short* attn  = (unsigned short*)(ws + 83886080);       // 16.78MB
    float*          bias3 = (float*)(ws + 100663296);               // 12KB
    float*          out   = (float*)d_out;

    hipLaunchKernelGGL(k_cast_bf16, dim3(4096), dim3(256), 0, stream, x, xb, 1048576);
    hipLaunchKernelGGL(k_cast_bf16, dim3(1536), dim3(256), 0, stream, Wqkv, Wqkvb, 393216);
    hipLaunchKernelGGL(k_build_bias, dim3(12), dim3(256), 0, stream, qbia, vbia, bias3);
    hipLaunchKernelGGL((k_gemm_lds<false, false>), dim3(64, 24), dim3(256), 0, stream,
                       xb, (const void*)Wqkvb, bias3, (void*)qkv, 3072, 1024);
    hipLaunchKernelGGL(k_norm_k, dim3(32768), dim3(256), 0, stream, qkv, kbuf);
    hipLaunchKernelGGL(k_vtrans, dim3(32, 64), dim3(256), 0, stream, qkv, vT);
    hipLaunchKernelGGL(k_attn, dim3(16, 64), dim3(256), 0, stream, qkv, kbuf, vT, sml, attn);
    hipLaunchKernelGGL((k_gemm_lds<true, true>), dim3(64, 8), dim3(256), 0, stream,
                       attn, (const void*)Wp, bp, (void*)out, 1024, 1024);
}

// Round 4
// 366.954 us; speedup vs baseline: 1.4424x; 1.4424x over previous
//
#include <hip/hip_runtime.h>
#include <hip/hip_bf16.h>

// Problem: B=4, L=2048, C=1024, H=16, D=64, M=B*L=8192. I/O f32.
// Internal: bf16 MFMA, f32 accumulate. R2 verified absmax 9.8e-4 (thr 4.04e-3).
// R4: attention rebuilt on 32x32x16 MFMA (2x FLOP/fragment-byte vs 16x16x32).

typedef __attribute__((ext_vector_type(8))) short bf16x8;
typedef __attribute__((ext_vector_type(4))) float f32x4;
typedef __attribute__((ext_vector_type(16))) float f32x16;

#define MAXLOG 4.60517018598809f   // ln(100)
#define LOG2E  1.4426950408889634f

__device__ __forceinline__ float bf2f(unsigned short u) {
    union { unsigned int i; float f; } v; v.i = ((unsigned int)u) << 16; return v.f;
}
__device__ __forceinline__ unsigned short f2bf(float f) {
    union { float f; unsigned int i; } v; v.f = f;
    unsigned int x = v.i;
    return (unsigned short)((x + 0x7FFFu + ((x >> 16) & 1u)) >> 16);  // RNE
}
__device__ __forceinline__ bf16x8 pack8(const float* __restrict__ p) {
    float4 a = *(const float4*)p;
    float4 b = *(const float4*)(p + 4);
    bf16x8 r;
    r[0] = (short)f2bf(a.x); r[1] = (short)f2bf(a.y);
    r[2] = (short)f2bf(a.z); r[3] = (short)f2bf(a.w);
    r[4] = (short)f2bf(b.x); r[5] = (short)f2bf(b.y);
    r[6] = (short)f2bf(b.z); r[7] = (short)f2bf(b.w);
    return r;
}
__device__ __forceinline__ void gload_lds16(const void* g, void* l) {
    __builtin_amdgcn_global_load_lds((const __attribute__((address_space(1))) void*)g,
                                     (__attribute__((address_space(3))) void*)l, 16, 0, 0);
}

// ------------------------------------------------------------ f32 -> bf16 cast
__global__ __launch_bounds__(256) void k_cast_bf16(const float* __restrict__ src,
                                                   unsigned short* __restrict__ dst, int n8) {
    int i = blockIdx.x * 256 + threadIdx.x;
    if (i < n8) *(bf16x8*)&dst[(long)i * 8] = pack8(&src[(long)i * 8]);
}

// ---------------------------------------------------------------- bias build
__global__ void k_build_bias(const float* __restrict__ qb, const float* __restrict__ vb,
                             float* __restrict__ bias3) {
    int i = blockIdx.x * 256 + threadIdx.x;
    if (i < 3072) {
        float v = 0.0f;
        if (i < 1024) v = qb[i];
        else if (i >= 2048) v = vb[i - 2048];
        bias3[i] = v;
    }
}

// --------------------------------------- GEMM, B^T input, global_load_lds staging
template<bool B_F32, bool OUT_F32>
__global__ __launch_bounds__(256) void k_gemm_lds(
    const unsigned short* __restrict__ A, const void* __restrict__ Bp,
    const float* __restrict__ bias, void* __restrict__ Cp, int N, int K)
{
    __shared__ unsigned short As[128 * 32];
    __shared__ unsigned short Bs[128 * 32];
    const int t = threadIdx.x, wave = t >> 6, lane = t & 63;
    const int quad = lane >> 4, l16 = lane & 15;
    const int bm = blockIdx.x * 128, bn = blockIdx.y * 128;
    const int wr = (wave >> 1) * 64, wc = (wave & 1) * 64;
    f32x4 acc[4][4] = {};

    const int srow = lane >> 2;
    const int scol = (lane & 3) * 8;
    const int c0 = wave * 2, c1 = wave * 2 + 1;
    const long ga0 = (long)(bm + c0 * 16 + srow) * K + scol;
    const long ga1 = (long)(bm + c1 * 16 + srow) * K + scol;
    const int sr = t >> 2, sc2 = (t & 3) * 8;
    const float* Bf = (const float*)Bp;
    const unsigned short* Bh = (const unsigned short*)Bp;
    const long gb0 = B_F32 ? ((long)(bn + sr) * K + sc2)      : ((long)(bn + c0 * 16 + srow) * K + scol);
    const long gb1 = B_F32 ? ((long)(bn + sr + 64) * K + sc2) : ((long)(bn + c1 * 16 + srow) * K + scol);

    for (int kt = 0; kt < K; kt += 32) {
        __syncthreads();
        gload_lds16(&A[ga0 + kt], &As[c0 * 512]);
        gload_lds16(&A[ga1 + kt], &As[c1 * 512]);
        if (B_F32) {
            *(bf16x8*)&Bs[sr * 32 + sc2]        = pack8(&Bf[gb0 + kt]);
            *(bf16x8*)&Bs[(sr + 64) * 32 + sc2] = pack8(&Bf[gb1 + kt]);
        } else {
            gload_lds16(&Bh[gb0 + kt], &Bs[c0 * 512]);
            gload_lds16(&Bh[gb1 + kt], &Bs[c1 * 512]);
        }
        __syncthreads();
        bf16x8 af[4], bfr[4];
        for (int i = 0; i < 4; ++i)
            af[i] = *(const bf16x8*)&As[(wr + i * 16 + l16) * 32 + quad * 8];
        for (int j = 0; j < 4; ++j)
            bfr[j] = *(const bf16x8*)&Bs[(wc + j * 16 + l16) * 32 + quad * 8];
        for (int i = 0; i < 4; ++i)
            for (int j = 0; j < 4; ++j)
                acc[i][j] = __builtin_amdgcn_mfma_f32_16x16x32_bf16(af[i], bfr[j], acc[i][j], 0, 0, 0);
    }
    for (int j = 0; j < 4; ++j) {
        int gn = bn + wc + j * 16 + l16;
        float bv = bias[gn];
        for (int i = 0; i < 4; ++i) {
            int gm0 = bm + wr + i * 16 + quad * 4;
            for (int r = 0; r < 4; ++r) {
                float val = acc[i][j][r] + bv;
                if (OUT_F32) ((float*)Cp)[(long)(gm0 + r) * N + gn] = val;
                else ((unsigned short*)Cp)[(long)(gm0 + r) * N + gn] = f2bf(val);
            }
        }
    }
}

// --------------------------------------------- k L2-normalize + head reshape
__global__ __launch_bounds__(256) void k_norm_k(
    const unsigned short* __restrict__ qkv, unsigned short* __restrict__ kb)
{
    const int wid = blockIdx.x * 4 + (threadIdx.x >> 6);
    const int lane = threadIdx.x & 63;
    const int h = wid & 15, m = wid >> 4;
    const int b = m >> 11, l = m & 2047;
    float kv = bf2f(qkv[(long)m * 3072 + 1024 + h * 64 + lane]);
    float sk = kv * kv;
    for (int s = 32; s; s >>= 1) sk += __shfl_xor(sk, s, 64);
    float kn = kv / fmaxf(sqrtf(sk), 1e-12f);
    kb[((long)(b * 16 + h) * 2048 + l) * 64 + lane] = f2bf(kn);
}

// --------------------------------------------------- v transpose to [B,H,D,L]
__global__ __launch_bounds__(256) void k_vtrans(
    const unsigned short* __restrict__ qkv, unsigned short* __restrict__ vT)
{
    __shared__ unsigned short Vsh[64 * 72];
    const int t = threadIdx.x;
    const int bh = blockIdx.y, l0 = blockIdx.x * 64;
    const int h = bh & 15, b = bh >> 4;
    const int ll = t >> 2, d0 = (t & 3) * 16;
    long src = (long)(b * 2048 + l0 + ll) * 3072 + 2048 + h * 64 + d0;
    *(bf16x8*)&Vsh[ll * 72 + d0]     = *(const bf16x8*)&qkv[src];
    *(bf16x8*)&Vsh[ll * 72 + d0 + 8] = *(const bf16x8*)&qkv[src + 8];
    __syncthreads();
    const int d = t >> 2, ls = (t & 3) * 16;
    unsigned short tmp[16];
    for (int j = 0; j < 16; ++j) tmp[j] = Vsh[(ls + j) * 72 + d];
    long dst = (long)(bh * 64 + d) * 2048 + l0 + ls;
    *(bf16x8*)&vT[dst]     = *(bf16x8*)&tmp[0];
    *(bf16x8*)&vT[dst + 8] = *(bf16x8*)&tmp[8];
}

// ------------------------------------------------------------ flash attention
// 32x32x16 MFMA. Wave = 32 q-rows; block = 4 waves = 128 rows. Fused q-norm.
// Constant shift c=scale (|q|=scale, |k|=1 => |S|<=scale): single pass.
// Layouts (32x32x16 bf16): A/B: row|n = lane&31, k = (lane>>5)*8+j.
//                          C/D: n = lane&31, m = (reg&3)+8*(reg>>2)+4*(lane>>5).
__global__ __launch_bounds__(256) void k_attn32(
    const unsigned short* __restrict__ qkv, const unsigned short* __restrict__ kb,
    const unsigned short* __restrict__ vT, const float* __restrict__ sml,
    unsigned short* __restrict__ attn)
{
    __shared__ unsigned short Ks[64 * 72];
    __shared__ unsigned short Vs[64 * 72];
    __shared__ unsigned short Ps[4 * 32 * 40];   // per-wave 32 rows x 32 keys (+pad)
    const int t = threadIdx.x, wave = t >> 6, lane = t & 63;
    const int m32 = lane & 31, half = lane >> 5;
    const int bh = blockIdx.y, h = bh & 15, b = bh >> 4;
    const int q0 = blockIdx.x * 128 + wave * 32;
    const float scale = __expf(fminf(sml[h], MAXLOG));
    const float c2 = scale * LOG2E;

    // fused q load + L2-normalize + scale into 4 A-frags (k-chunks of 16)
    bf16x8 aq[4];
    {
        long base = (long)(b * 2048 + q0 + m32) * 3072 + h * 64;
        float e[32]; float ss = 0.f;
        for (int f = 0; f < 4; ++f) {
            aq[f] = *(const bf16x8*)&qkv[base + f * 16 + half * 8];
            for (int j = 0; j < 8; ++j) { float x = bf2f((unsigned short)aq[f][j]); e[f * 8 + j] = x; ss += x * x; }
        }
        ss += __shfl_xor(ss, 32, 64);   // partner lane holds the other 32 elems of row m32
        float rs = scale / fmaxf(sqrtf(ss), 1e-12f);
        for (int f = 0; f < 4; ++f)
            for (int j = 0; j < 8; ++j) aq[f][j] = (short)f2bf(e[f * 8 + j] * rs);
    }

    f32x16 o0 = {}, o1 = {}, lacc = {};
    bf16x8 ones; for (int i = 0; i < 8; ++i) ones[i] = (short)0x3F80;
    unsigned short* Pw = &Ps[wave * 1280];
    const int sr = t >> 2, sc = (t & 3) * 16;

    for (int kt = 0; kt < 2048; kt += 64) {
        __syncthreads();
        long ksrc = ((long)bh * 2048 + kt + sr) * 64 + sc;
        *(bf16x8*)&Ks[sr * 72 + sc]     = *(const bf16x8*)&kb[ksrc];
        *(bf16x8*)&Ks[sr * 72 + sc + 8] = *(const bf16x8*)&kb[ksrc + 8];
        long vsrc = ((long)bh * 64 + sr) * 2048 + kt + sc;
        *(bf16x8*)&Vs[sr * 72 + sc]     = *(const bf16x8*)&vT[vsrc];
        *(bf16x8*)&Vs[sr * 72 + sc + 8] = *(const bf16x8*)&vT[vsrc + 8];
        __syncthreads();

        for (int ktile = 0; ktile < 2; ++ktile) {
            // S tile: 32 q-rows x 32 keys, K-dim 64 in 4 chunks
            f32x16 s = {};
            for (int f = 0; f < 4; ++f) {
                bf16x8 bk = *(const bf16x8*)&Ks[(ktile * 32 + m32) * 72 + f * 16 + half * 8];
                s = __builtin_amdgcn_mfma_f32_32x32x16_bf16(aq[f], bk, s, 0, 0, 0);
            }
            // P = exp2(S*log2e - c2), C-layout -> wave-private LDS
            for (int r = 0; r < 16; ++r) {
                int m = (r & 3) + 8 * (r >> 2) + 4 * half;
                union { float f; unsigned int u; } cv;
                cv.f = __builtin_amdgcn_exp2f(s[r] * LOG2E - c2);
                Pw[m * 40 + m32] = (unsigned short)(cv.u >> 16);
            }
            // A-layout P frags (k = keys within this 32-key tile)
            bf16x8 ap0 = *(const bf16x8*)&Pw[m32 * 40 + half * 8];
            bf16x8 ap1 = *(const bf16x8*)&Pw[m32 * 40 + 16 + half * 8];
            for (int c = 0; c < 2; ++c) {
                bf16x8 apc = c ? ap1 : ap0;
                bf16x8 bv0 = *(const bf16x8*)&Vs[m32 * 72        + ktile * 32 + c * 16 + half * 8];
                bf16x8 bv1 = *(const bf16x8*)&Vs[(32 + m32) * 72 + ktile * 32 + c * 16 + half * 8];
                o0   = __builtin_amdgcn_mfma_f32_32x32x16_bf16(apc, bv0, o0, 0, 0, 0);
                o1   = __builtin_amdgcn_mfma_f32_32x32x16_bf16(apc, bv1, o1, 0, 0, 0);
                lacc = __builtin_amdgcn_mfma_f32_32x32x16_bf16(apc, ones, lacc, 0, 0, 0);
            }
        }
    }
    // epilogue: divide by rowsum, write attn[B,L,C]
    for (int r = 0; r < 16; ++r) {
        int m = (r & 3) + 8 * (r >> 2) + 4 * half;
        float inv = 1.0f / lacc[r];
        long dst = (long)(b * 2048 + q0 + m) * 1024 + h * 64;
        attn[dst + m32]      = f2bf(o0[r] * inv);
        attn[dst + 32 + m32] = f2bf(o1[r] * inv);
    }
}

// ---------------------------------------------------------------------------
extern "C" void kernel_launch(void* const* d_in, const int* in_sizes, int n_in,
                              void* d_out, int out_size, void* d_ws, size_t ws_size,
                              hipStream_t stream) {
    const float* x    = (const float*)d_in[0];
    const float* Wqkv = (const float*)d_in[1];
    const float* qbia = (const float*)d_in[2];
    const float* vbia = (const float*)d_in[3];
    const float* sml  = (const float*)d_in[4];
    const float* Wp   = (const float*)d_in[5];
    const float* bp   = (const float*)d_in[6];

    char* ws = (char*)d_ws;
    unsigned short* qkv   = (unsigned short*)ws;                    // [0, 50.33MB)
    unsigned short* kbuf  = (unsigned short*)(ws + 50331648);       // hosts Wqkvb first
    unsigned short* Wqkvb = kbuf;
    unsigned short* vT    = (unsigned short*)(ws + 67108864);       // hosts xb first
    unsigned short* xb    = vT;
    unsigned short* attn  = (unsigned short*)(ws + 83886080);
    float*          bias3 = (float*)(ws + 100663296);
    float*          out   = (float*)d_out;

    hipLaunchKernelGGL(k_cast_bf16, dim3(4096), dim3(256), 0, stream, x, xb, 1048576);
    hipLaunchKernelGGL(k_cast_bf16, dim3(1536), dim3(256), 0, stream, Wqkv, Wqkvb, 393216);
    hipLaunchKernelGGL(k_build_bias, dim3(12), dim3(256), 0, stream, qbia, vbia, bias3);
    hipLaunchKernelGGL((k_gemm_lds<false, false>), dim3(64, 24), dim3(256), 0, stream,
                       xb, (const void*)Wqkvb, bias3, (void*)qkv, 3072, 1024);
    hipLaunchKernelGGL(k_norm_k, dim3(32768), dim3(256), 0, stream, qkv, kbuf);
    hipLaunchKernelGGL(k_vtrans, dim3(32, 64), dim3(256), 0, stream, qkv, vT);
    hipLaunchKernelGGL(k_attn32, dim3(16, 64), dim3(256), 0, stream, qkv, kbuf, vT, sml, attn);
    hipLaunchKernelGGL((k_gemm_lds<true, true>), dim3(64, 8), dim3(256), 0, stream,
                       attn, (const void*)Wp, bp, (void*)out, 1024, 1024);
}

// Round 5
// 337.195 us; speedup vs baseline: 1.5697x; 1.0883x over previous
//
#include <hip/hip_runtime.h>
#include <hip/hip_bf16.h>

// Problem: B=4, L=2048, C=1024, H=16, D=64, M=B*L=8192. I/O f32.
// Internal: bf16 MFMA, f32 accumulate. R2 verified absmax 9.8e-4 (thr 4.04e-3).
// R5: S^T-form attention — P never touches LDS (key-permutation trick).

typedef __attribute__((ext_vector_type(8))) short bf16x8;
typedef __attribute__((ext_vector_type(4))) float f32x4;
typedef __attribute__((ext_vector_type(16))) float f32x16;

#define MAXLOG 4.60517018598809f   // ln(100)
#define LOG2E  1.4426950408889634f

__device__ __forceinline__ float bf2f(unsigned short u) {
    union { unsigned int i; float f; } v; v.i = ((unsigned int)u) << 16; return v.f;
}
__device__ __forceinline__ unsigned short f2bf(float f) {
    union { float f; unsigned int i; } v; v.f = f;
    unsigned int x = v.i;
    return (unsigned short)((x + 0x7FFFu + ((x >> 16) & 1u)) >> 16);  // RNE
}
__device__ __forceinline__ bf16x8 pack8(const float* __restrict__ p) {
    float4 a = *(const float4*)p;
    float4 b = *(const float4*)(p + 4);
    bf16x8 r;
    r[0] = (short)f2bf(a.x); r[1] = (short)f2bf(a.y);
    r[2] = (short)f2bf(a.z); r[3] = (short)f2bf(a.w);
    r[4] = (short)f2bf(b.x); r[5] = (short)f2bf(b.y);
    r[6] = (short)f2bf(b.z); r[7] = (short)f2bf(b.w);
    return r;
}
__device__ __forceinline__ void gload_lds16(const void* g, void* l) {
    __builtin_amdgcn_global_load_lds((const __attribute__((address_space(1))) void*)g,
                                     (__attribute__((address_space(3))) void*)l, 16, 0, 0);
}

// ------------------------------------------------------------ f32 -> bf16 cast
__global__ __launch_bounds__(256) void k_cast_bf16(const float* __restrict__ src,
                                                   unsigned short* __restrict__ dst, int n8) {
    int i = blockIdx.x * 256 + threadIdx.x;
    if (i < n8) *(bf16x8*)&dst[(long)i * 8] = pack8(&src[(long)i * 8]);
}

// ---------------------------------------------------------------- bias build
__global__ void k_build_bias(const float* __restrict__ qb, const float* __restrict__ vb,
                             float* __restrict__ bias3) {
    int i = blockIdx.x * 256 + threadIdx.x;
    if (i < 3072) {
        float v = 0.0f;
        if (i < 1024) v = qb[i];
        else if (i >= 2048) v = vb[i - 2048];
        bias3[i] = v;
    }
}

// --------------------------------------- GEMM, B^T input, global_load_lds staging
template<bool B_F32, bool OUT_F32>
__global__ __launch_bounds__(256) void k_gemm_lds(
    const unsigned short* __restrict__ A, const void* __restrict__ Bp,
    const float* __restrict__ bias, void* __restrict__ Cp, int N, int K)
{
    __shared__ unsigned short As[128 * 32];
    __shared__ unsigned short Bs[128 * 32];
    const int t = threadIdx.x, wave = t >> 6, lane = t & 63;
    const int quad = lane >> 4, l16 = lane & 15;
    const int bm = blockIdx.x * 128, bn = blockIdx.y * 128;
    const int wr = (wave >> 1) * 64, wc = (wave & 1) * 64;
    f32x4 acc[4][4] = {};

    const int srow = lane >> 2;
    const int scol = (lane & 3) * 8;
    const int c0 = wave * 2, c1 = wave * 2 + 1;
    const long ga0 = (long)(bm + c0 * 16 + srow) * K + scol;
    const long ga1 = (long)(bm + c1 * 16 + srow) * K + scol;
    const int sr = t >> 2, sc2 = (t & 3) * 8;
    const float* Bf = (const float*)Bp;
    const unsigned short* Bh = (const unsigned short*)Bp;
    const long gb0 = B_F32 ? ((long)(bn + sr) * K + sc2)      : ((long)(bn + c0 * 16 + srow) * K + scol);
    const long gb1 = B_F32 ? ((long)(bn + sr + 64) * K + sc2) : ((long)(bn + c1 * 16 + srow) * K + scol);

    for (int kt = 0; kt < K; kt += 32) {
        __syncthreads();
        gload_lds16(&A[ga0 + kt], &As[c0 * 512]);
        gload_lds16(&A[ga1 + kt], &As[c1 * 512]);
        if (B_F32) {
            *(bf16x8*)&Bs[sr * 32 + sc2]        = pack8(&Bf[gb0 + kt]);
            *(bf16x8*)&Bs[(sr + 64) * 32 + sc2] = pack8(&Bf[gb1 + kt]);
        } else {
            gload_lds16(&Bh[gb0 + kt], &Bs[c0 * 512]);
            gload_lds16(&Bh[gb1 + kt], &Bs[c1 * 512]);
        }
        __syncthreads();
        bf16x8 af[4], bfr[4];
        for (int i = 0; i < 4; ++i)
            af[i] = *(const bf16x8*)&As[(wr + i * 16 + l16) * 32 + quad * 8];
        for (int j = 0; j < 4; ++j)
            bfr[j] = *(const bf16x8*)&Bs[(wc + j * 16 + l16) * 32 + quad * 8];
        for (int i = 0; i < 4; ++i)
            for (int j = 0; j < 4; ++j)
                acc[i][j] = __builtin_amdgcn_mfma_f32_16x16x32_bf16(af[i], bfr[j], acc[i][j], 0, 0, 0);
    }
    for (int j = 0; j < 4; ++j) {
        int gn = bn + wc + j * 16 + l16;
        float bv = bias[gn];
        for (int i = 0; i < 4; ++i) {
            int gm0 = bm + wr + i * 16 + quad * 4;
            for (int r = 0; r < 4; ++r) {
                float val = acc[i][j][r] + bv;
                if (OUT_F32) ((float*)Cp)[(long)(gm0 + r) * N + gn] = val;
                else ((unsigned short*)Cp)[(long)(gm0 + r) * N + gn] = f2bf(val);
            }
        }
    }
}

// --------------------------------------------- k L2-normalize + head reshape
__global__ __launch_bounds__(256) void k_norm_k(
    const unsigned short* __restrict__ qkv, unsigned short* __restrict__ kb)
{
    const int wid = blockIdx.x * 4 + (threadIdx.x >> 6);
    const int lane = threadIdx.x & 63;
    const int h = wid & 15, m = wid >> 4;
    const int b = m >> 11, l = m & 2047;
    float kv = bf2f(qkv[(long)m * 3072 + 1024 + h * 64 + lane]);
    float sk = kv * kv;
    for (int s = 32; s; s >>= 1) sk += __shfl_xor(sk, s, 64);
    float kn = kv / fmaxf(sqrtf(sk), 1e-12f);
    kb[((long)(b * 16 + h) * 2048 + l) * 64 + lane] = f2bf(kn);
}

// --------------------------------------------------- v transpose to [B,H,D,L]
__global__ __launch_bounds__(256) void k_vtrans(
    const unsigned short* __restrict__ qkv, unsigned short* __restrict__ vT)
{
    __shared__ unsigned short Vsh[64 * 72];
    const int t = threadIdx.x;
    const int bh = blockIdx.y, l0 = blockIdx.x * 64;
    const int h = bh & 15, b = bh >> 4;
    const int ll = t >> 2, d0 = (t & 3) * 16;
    long src = (long)(b * 2048 + l0 + ll) * 3072 + 2048 + h * 64 + d0;
    *(bf16x8*)&Vsh[ll * 72 + d0]     = *(const bf16x8*)&qkv[src];
    *(bf16x8*)&Vsh[ll * 72 + d0 + 8] = *(const bf16x8*)&qkv[src + 8];
    __syncthreads();
    const int d = t >> 2, ls = (t & 3) * 16;
    unsigned short tmp[16];
    for (int j = 0; j < 16; ++j) tmp[j] = Vsh[(ls + j) * 72 + d];
    long dst = (long)(bh * 64 + d) * 2048 + l0 + ls;
    *(bf16x8*)&vT[dst]     = *(bf16x8*)&tmp[0];
    *(bf16x8*)&vT[dst + 8] = *(bf16x8*)&tmp[8];
}

// ------------------------------------------------------------ flash attention
// 32x32x16 MFMA, S^T form. Wave = 32 q-rows; block = 128 rows. Fused q-norm.
// Constant shift c=scale (|q|=scale, |k|=1 => |S|<=scale): single pass.
// S^T = MFMA(A=K-frag(perm rows), B=q-frag): C/D col=lane&31=qrow,
// row=(r&3)+8*(r>>2)+4*half = logical key m. With key permutation
// pi(m): swap quads 1<->2 and 5<->6, reg r directly holds P[qrow][key] in
// PV-A-frag order: ap0=regs0..7, ap1=regs8..15. P never touches LDS.
__global__ __launch_bounds__(256) void k_attn32(
    const unsigned short* __restrict__ qkv, const unsigned short* __restrict__ kb,
    const unsigned short* __restrict__ vT, const float* __restrict__ sml,
    unsigned short* __restrict__ attn)
{
    __shared__ unsigned short Ks[64 * 72];
    __shared__ unsigned short Vs[64 * 72];
    const int t = threadIdx.x, wave = t >> 6, lane = t & 63;
    const int m32 = lane & 31, half = lane >> 5;
    const int bh = blockIdx.y, h = bh & 15, b = bh >> 4;
    const int q0 = blockIdx.x * 128 + wave * 32;
    const float scale = __expf(fminf(sml[h], MAXLOG));
    const float c2 = scale * LOG2E;

    // permuted physical key row for the S^T A-frag
    const int qd = m32 >> 2, lo = qd & 3;
    const int prow = ((((lo == 1) || (lo == 2)) ? (qd ^ 3) : qd) << 2) | (m32 & 3);

    // fused q load + L2-normalize + scale (B-frag; same lane layout as A-frag)
    bf16x8 aq[4];
    {
        long base = (long)(b * 2048 + q0 + m32) * 3072 + h * 64;
        float e[32]; float ss = 0.f;
        for (int f = 0; f < 4; ++f) {
            aq[f] = *(const bf16x8*)&qkv[base + f * 16 + half * 8];
            for (int j = 0; j < 8; ++j) { float x = bf2f((unsigned short)aq[f][j]); e[f * 8 + j] = x; ss += x * x; }
        }
        ss += __shfl_xor(ss, 32, 64);
        float rs = scale / fmaxf(sqrtf(ss), 1e-12f);
        for (int f = 0; f < 4; ++f)
            for (int j = 0; j < 8; ++j) aq[f][j] = (short)f2bf(e[f * 8 + j] * rs);
    }

    f32x16 o0 = {}, o1 = {}, lacc = {};
    bf16x8 ones; for (int i = 0; i < 8; ++i) ones[i] = (short)0x3F80;
    const int sr = t >> 2, sc = (t & 3) * 16;

    for (int kt = 0; kt < 2048; kt += 64) {
        __syncthreads();
        long ksrc = ((long)bh * 2048 + kt + sr) * 64 + sc;
        *(bf16x8*)&Ks[sr * 72 + sc]     = *(const bf16x8*)&kb[ksrc];
        *(bf16x8*)&Ks[sr * 72 + sc + 8] = *(const bf16x8*)&kb[ksrc + 8];
        long vsrc = ((long)bh * 64 + sr) * 2048 + kt + sc;
        *(bf16x8*)&Vs[sr * 72 + sc]     = *(const bf16x8*)&vT[vsrc];
        *(bf16x8*)&Vs[sr * 72 + sc + 8] = *(const bf16x8*)&vT[vsrc + 8];
        __syncthreads();

        for (int ktile = 0; ktile < 2; ++ktile) {
            // S^T tile: A = K rows (permuted), B = q
            f32x16 s = {};
            for (int f = 0; f < 4; ++f) {
                bf16x8 bk = *(const bf16x8*)&Ks[(ktile * 32 + prow) * 72 + f * 16 + half * 8];
                s = __builtin_amdgcn_mfma_f32_32x32x16_bf16(bk, aq[f], s, 0, 0, 0);
            }
            // P = exp2(S*log2e - c2) in-register; regs 0..7 -> ap0, 8..15 -> ap1
            bf16x8 ap0, ap1;
            for (int j = 0; j < 8; ++j) {
                union { float f; unsigned int u; } cv;
                cv.f = __builtin_amdgcn_exp2f(s[j] * LOG2E - c2);
                ap0[j] = (short)(cv.u >> 16);
                cv.f = __builtin_amdgcn_exp2f(s[8 + j] * LOG2E - c2);
                ap1[j] = (short)(cv.u >> 16);
            }
            // O += P V ; l += rowsum(P)
            for (int c = 0; c < 2; ++c) {
                bf16x8 apc = c ? ap1 : ap0;
                bf16x8 bv0 = *(const bf16x8*)&Vs[m32 * 72        + ktile * 32 + c * 16 + half * 8];
                bf16x8 bv1 = *(const bf16x8*)&Vs[(32 + m32) * 72 + ktile * 32 + c * 16 + half * 8];
                o0   = __builtin_amdgcn_mfma_f32_32x32x16_bf16(apc, bv0, o0, 0, 0, 0);
                o1   = __builtin_amdgcn_mfma_f32_32x32x16_bf16(apc, bv1, o1, 0, 0, 0);
                lacc = __builtin_amdgcn_mfma_f32_32x32x16_bf16(apc, ones, lacc, 0, 0, 0);
            }
        }
    }
    // epilogue: divide by rowsum, write attn[B,L,C]
    for (int r = 0; r < 16; ++r) {
        int m = (r & 3) + 8 * (r >> 2) + 4 * half;
        float inv = 1.0f / lacc[r];
        long dst = (long)(b * 2048 + q0 + m) * 1024 + h * 64;
        attn[dst + m32]      = f2bf(o0[r] * inv);
        attn[dst + 32 + m32] = f2bf(o1[r] * inv);
    }
}

// ---------------------------------------------------------------------------
extern "C" void kernel_launch(void* const* d_in, const int* in_sizes, int n_in,
                              void* d_out, int out_size, void* d_ws, size_t ws_size,
                              hipStream_t stream) {
    const float* x    = (const float*)d_in[0];
    const float* Wqkv = (const float*)d_in[1];
    const float* qbia = (const float*)d_in[2];
    const float* vbia = (const float*)d_in[3];
    const float* sml  = (const float*)d_in[4];
    const float* Wp   = (const float*)d_in[5];
    const float* bp   = (const float*)d_in[6];

    char* ws = (char*)d_ws;
    unsigned short* qkv   = (unsigned short*)ws;                    // [0, 50.33MB)
    unsigned short* kbuf  = (unsigned short*)(ws + 50331648);       // hosts Wqkvb first
    unsigned short* Wqkvb = kbuf;
    unsigned short* vT    = (unsigned short*)(ws + 67108864);       // hosts xb first
    unsigned short* xb    = vT;
    unsigned short* attn  = (unsigned short*)(ws + 83886080);
    float*          bias3 = (float*)(ws + 100663296);
    float*          out   = (float*)d_out;

    hipLaunchKernelGGL(k_cast_bf16, dim3(4096), dim3(256), 0, stream, x, xb, 1048576);
    hipLaunchKernelGGL(k_cast_bf16, dim3(1536), dim3(256), 0, stream, Wqkv, Wqkvb, 393216);
    hipLaunchKernelGGL(k_build_bias, dim3(12), dim3(256), 0, stream, qbia, vbia, bias3);
    hipLaunchKernelGGL((k_gemm_lds<false, false>), dim3(64, 24), dim3(256), 0, stream,
                       xb, (const void*)Wqkvb, bias3, (void*)qkv, 3072, 1024);
    hipLaunchKernelGGL(k_norm_k, dim3(32768), dim3(256), 0, stream, qkv, kbuf);
    hipLaunchKernelGGL(k_vtrans, dim3(32, 64), dim3(256), 0, stream, qkv, vT);
    hipLaunchKernelGGL(k_attn32, dim3(16, 64), dim3(256), 0, stream, qkv, kbuf, vT, sml, attn);
    hipLaunchKernelGGL((k_gemm_lds<true, true>), dim3(64, 8), dim3(256), 0, stream,
                       attn, (const void*)Wp, bp, (void*)out, 1024, 1024);
}

// Round 6
// 321.827 us; speedup vs baseline: 1.6446x; 1.0477x over previous
//
#include <hip/hip_runtime.h>
#include <hip/hip_bf16.h>

// Problem: B=4, L=2048, C=1024, H=16, D=64, M=B*L=8192. I/O f32.
// Internal: bf16 MFMA, f32 accumulate. R5 verified absmax 9.8e-4 (thr 4.04e-3).
// R6: attn — drop ones-MFMA (VALU rowsum + shfl redistribute), v_perm packing,
//     double-buffered K/V LDS with register prefetch; proj GEMM all-bf16.

typedef __attribute__((ext_vector_type(8))) short bf16x8;
typedef __attribute__((ext_vector_type(4))) float f32x4;
typedef __attribute__((ext_vector_type(16))) float f32x16;

#define MAXLOG 4.60517018598809f   // ln(100)
#define LOG2E  1.4426950408889634f

__device__ __forceinline__ float bf2f(unsigned short u) {
    union { unsigned int i; float f; } v; v.i = ((unsigned int)u) << 16; return v.f;
}
__device__ __forceinline__ unsigned short f2bf(float f) {
    union { float f; unsigned int i; } v; v.f = f;
    unsigned int x = v.i;
    return (unsigned short)((x + 0x7FFFu + ((x >> 16) & 1u)) >> 16);  // RNE
}
__device__ __forceinline__ unsigned fbits(float f) {
    union { float f; unsigned u; } v; v.f = f; return v.u;
}
__device__ __forceinline__ bf16x8 pack8(const float* __restrict__ p) {
    float4 a = *(const float4*)p;
    float4 b = *(const float4*)(p + 4);
    bf16x8 r;
    r[0] = (short)f2bf(a.x); r[1] = (short)f2bf(a.y);
    r[2] = (short)f2bf(a.z); r[3] = (short)f2bf(a.w);
    r[4] = (short)f2bf(b.x); r[5] = (short)f2bf(b.y);
    r[6] = (short)f2bf(b.z); r[7] = (short)f2bf(b.w);
    return r;
}
__device__ __forceinline__ void gload_lds16(const void* g, void* l) {
    __builtin_amdgcn_global_load_lds((const __attribute__((address_space(1))) void*)g,
                                     (__attribute__((address_space(3))) void*)l, 16, 0, 0);
}

// ------------------------------------------------------------ f32 -> bf16 cast
__global__ __launch_bounds__(256) void k_cast_bf16(const float* __restrict__ src,
                                                   unsigned short* __restrict__ dst, int n8) {
    int i = blockIdx.x * 256 + threadIdx.x;
    if (i < n8) *(bf16x8*)&dst[(long)i * 8] = pack8(&src[(long)i * 8]);
}

// ---------------------------------------------------------------- bias build
__global__ void k_build_bias(const float* __restrict__ qb, const float* __restrict__ vb,
                             float* __restrict__ bias3) {
    int i = blockIdx.x * 256 + threadIdx.x;
    if (i < 3072) {
        float v = 0.0f;
        if (i < 1024) v = qb[i];
        else if (i >= 2048) v = vb[i - 2048];
        bias3[i] = v;
    }
}

// --------------------------------------- GEMM, B^T input, global_load_lds staging
template<bool B_F32, bool OUT_F32>
__global__ __launch_bounds__(256) void k_gemm_lds(
    const unsigned short* __restrict__ A, const void* __restrict__ Bp,
    const float* __restrict__ bias, void* __restrict__ Cp, int N, int K)
{
    __shared__ unsigned short As[128 * 32];
    __shared__ unsigned short Bs[128 * 32];
    const int t = threadIdx.x, wave = t >> 6, lane = t & 63;
    const int quad = lane >> 4, l16 = lane & 15;
    const int bm = blockIdx.x * 128, bn = blockIdx.y * 128;
    const int wr = (wave >> 1) * 64, wc = (wave & 1) * 64;
    f32x4 acc[4][4] = {};

    const int srow = lane >> 2;
    const int scol = (lane & 3) * 8;
    const int c0 = wave * 2, c1 = wave * 2 + 1;
    const long ga0 = (long)(bm + c0 * 16 + srow) * K + scol;
    const long ga1 = (long)(bm + c1 * 16 + srow) * K + scol;
    const int sr = t >> 2, sc2 = (t & 3) * 8;
    const float* Bf = (const float*)Bp;
    const unsigned short* Bh = (const unsigned short*)Bp;
    const long gb0 = B_F32 ? ((long)(bn + sr) * K + sc2)      : ((long)(bn + c0 * 16 + srow) * K + scol);
    const long gb1 = B_F32 ? ((long)(bn + sr + 64) * K + sc2) : ((long)(bn + c1 * 16 + srow) * K + scol);

    for (int kt = 0; kt < K; kt += 32) {
        __syncthreads();
        gload_lds16(&A[ga0 + kt], &As[c0 * 512]);
        gload_lds16(&A[ga1 + kt], &As[c1 * 512]);
        if (B_F32) {
            *(bf16x8*)&Bs[sr * 32 + sc2]        = pack8(&Bf[gb0 + kt]);
            *(bf16x8*)&Bs[(sr + 64) * 32 + sc2] = pack8(&Bf[gb1 + kt]);
        } else {
            gload_lds16(&Bh[gb0 + kt], &Bs[c0 * 512]);
            gload_lds16(&Bh[gb1 + kt], &Bs[c1 * 512]);
        }
        __syncthreads();
        bf16x8 af[4], bfr[4];
        for (int i = 0; i < 4; ++i)
            af[i] = *(const bf16x8*)&As[(wr + i * 16 + l16) * 32 + quad * 8];
        for (int j = 0; j < 4; ++j)
            bfr[j] = *(const bf16x8*)&Bs[(wc + j * 16 + l16) * 32 + quad * 8];
        for (int i = 0; i < 4; ++i)
            for (int j = 0; j < 4; ++j)
                acc[i][j] = __builtin_amdgcn_mfma_f32_16x16x32_bf16(af[i], bfr[j], acc[i][j], 0, 0, 0);
    }
    for (int j = 0; j < 4; ++j) {
        int gn = bn + wc + j * 16 + l16;
        float bv = bias[gn];
        for (int i = 0; i < 4; ++i) {
            int gm0 = bm + wr + i * 16 + quad * 4;
            for (int r = 0; r < 4; ++r) {
                float val = acc[i][j][r] + bv;
                if (OUT_F32) ((float*)Cp)[(long)(gm0 + r) * N + gn] = val;
                else ((unsigned short*)Cp)[(long)(gm0 + r) * N + gn] = f2bf(val);
            }
        }
    }
}

// --------------------------------------------- k L2-normalize + head reshape
__global__ __launch_bounds__(256) void k_norm_k(
    const unsigned short* __restrict__ qkv, unsigned short* __restrict__ kb)
{
    const int wid = blockIdx.x * 4 + (threadIdx.x >> 6);
    const int lane = threadIdx.x & 63;
    const int h = wid & 15, m = wid >> 4;
    const int b = m >> 11, l = m & 2047;
    float kv = bf2f(qkv[(long)m * 3072 + 1024 + h * 64 + lane]);
    float sk = kv * kv;
    for (int s = 32; s; s >>= 1) sk += __shfl_xor(sk, s, 64);
    float kn = kv / fmaxf(sqrtf(sk), 1e-12f);
    kb[((long)(b * 16 + h) * 2048 + l) * 64 + lane] = f2bf(kn);
}

// --------------------------------------------------- v transpose to [B,H,D,L]
__global__ __launch_bounds__(256) void k_vtrans(
    const unsigned short* __restrict__ qkv, unsigned short* __restrict__ vT)
{
    __shared__ unsigned short Vsh[64 * 72];
    const int t = threadIdx.x;
    const int bh = blockIdx.y, l0 = blockIdx.x * 64;
    const int h = bh & 15, b = bh >> 4;
    const int ll = t >> 2, d0 = (t & 3) * 16;
    long src = (long)(b * 2048 + l0 + ll) * 3072 + 2048 + h * 64 + d0;
    *(bf16x8*)&Vsh[ll * 72 + d0]     = *(const bf16x8*)&qkv[src];
    *(bf16x8*)&Vsh[ll * 72 + d0 + 8] = *(const bf16x8*)&qkv[src + 8];
    __syncthreads();
    const int d = t >> 2, ls = (t & 3) * 16;
    unsigned short tmp[16];
    for (int j = 0; j < 16; ++j) tmp[j] = Vsh[(ls + j) * 72 + d];
    long dst = (long)(bh * 64 + d) * 2048 + l0 + ls;
    *(bf16x8*)&vT[dst]     = *(bf16x8*)&tmp[0];
    *(bf16x8*)&vT[dst + 8] = *(bf16x8*)&tmp[8];
}

// ------------------------------------------------------------ flash attention
// 32x32x16 MFMA, S^T form (R5 key-permutation: P stays in registers).
// R6: no ones-MFMA (VALU rowsum), v_perm pack, double-buffered K/V LDS.
__global__ __launch_bounds__(256, 3) void k_attn32(
    const unsigned short* __restrict__ qkv, const unsigned short* __restrict__ kb,
    const unsigned short* __restrict__ vT, const float* __restrict__ sml,
    unsigned short* __restrict__ attn)
{
    __shared__ unsigned short Ks[2][64 * 72];
    __shared__ unsigned short Vs[2][64 * 72];
    const int t = threadIdx.x, wave = t >> 6, lane = t & 63;
    const int m32 = lane & 31, half = lane >> 5;
    const int bh = blockIdx.y, h = bh & 15, b = bh >> 4;
    const int q0 = blockIdx.x * 128 + wave * 32;
    const float scale = __expf(fminf(sml[h], MAXLOG));
    const float c2 = scale * LOG2E;

    // permuted physical key row for the S^T A-frag (swap quads 1<->2, 5<->6)
    const int qd = m32 >> 2, lo = qd & 3;
    const int prow = ((((lo == 1) || (lo == 2)) ? (qd ^ 3) : qd) << 2) | (m32 & 3);

    // fused q load + L2-normalize + scale (B-frag layout)
    bf16x8 aq[4];
    {
        long base = (long)(b * 2048 + q0 + m32) * 3072 + h * 64;
        float e[32]; float ss = 0.f;
        for (int f = 0; f < 4; ++f) {
            aq[f] = *(const bf16x8*)&qkv[base + f * 16 + half * 8];
            for (int j = 0; j < 8; ++j) { float x = bf2f((unsigned short)aq[f][j]); e[f * 8 + j] = x; ss += x * x; }
        }
        ss += __shfl_xor(ss, 32, 64);
        float rs = scale / fmaxf(sqrtf(ss), 1e-12f);
        for (int f = 0; f < 4; ++f)
            for (int j = 0; j < 8; ++j) aq[f][j] = (short)f2bf(e[f * 8 + j] * rs);
    }

    f32x16 o0 = {}, o1 = {};
    float ps0 = 0.f, ps1 = 0.f;
    const int sr = t >> 2, sc = (t & 3) * 16;
    const long kbase = (long)bh * 2048 * 64;
    const long vbase = (long)bh * 64 * 2048;

#define LOADT(kt) \
    kpA = *(const bf16x8*)&kb[kbase + (long)((kt) + sr) * 64 + sc];      \
    kpB = *(const bf16x8*)&kb[kbase + (long)((kt) + sr) * 64 + sc + 8];  \
    vpA = *(const bf16x8*)&vT[vbase + (long)sr * 2048 + (kt) + sc];      \
    vpB = *(const bf16x8*)&vT[vbase + (long)sr * 2048 + (kt) + sc + 8];

#define STORET(buf) \
    *(bf16x8*)&Ks[buf][sr * 72 + sc]     = kpA;  \
    *(bf16x8*)&Ks[buf][sr * 72 + sc + 8] = kpB;  \
    *(bf16x8*)&Vs[buf][sr * 72 + sc]     = vpA;  \
    *(bf16x8*)&Vs[buf][sr * 72 + sc + 8] = vpB;

#define ATTN_STEP(KS, VS) \
    for (int ktile = 0; ktile < 2; ++ktile) {                                             \
        f32x16 s = {};                                                                    \
        for (int f = 0; f < 4; ++f) {                                                     \
            bf16x8 bk = *(const bf16x8*)&KS[(ktile * 32 + prow) * 72 + f * 16 + half * 8];\
            s = __builtin_amdgcn_mfma_f32_32x32x16_bf16(bk, aq[f], s, 0, 0, 0);           \
        }                                                                                 \
        unsigned pu[16];                                                                  \
        for (int j = 0; j < 8; ++j) {                                                     \
            float ea = __builtin_amdgcn_exp2f(s[j] * LOG2E - c2);                         \
            float eb = __builtin_amdgcn_exp2f(s[8 + j] * LOG2E - c2);                     \
            ps0 += ea; ps1 += eb;                                                         \
            pu[j] = fbits(ea) + 0x8000u; pu[8 + j] = fbits(eb) + 0x8000u;                 \
        }                                                                                 \
        uint4 a0u, a1u;                                                                   \
        a0u.x = __builtin_amdgcn_perm(pu[1],  pu[0],  0x07060302u);                       \
        a0u.y = __builtin_amdgcn_perm(pu[3],  pu[2],  0x07060302u);                       \
        a0u.z = __builtin_amdgcn_perm(pu[5],  pu[4],  0x07060302u);                       \
        a0u.w = __builtin_amdgcn_perm(pu[7],  pu[6],  0x07060302u);                       \
        a1u.x = __builtin_amdgcn_perm(pu[9],  pu[8],  0x07060302u);                       \
        a1u.y = __builtin_amdgcn_perm(pu[11], pu[10], 0x07060302u);                       \
        a1u.z = __builtin_amdgcn_perm(pu[13], pu[12], 0x07060302u);                       \
        a1u.w = __builtin_amdgcn_perm(pu[15], pu[14], 0x07060302u);                       \
        bf16x8 ap0, ap1;                                                                  \
        __builtin_memcpy(&ap0, &a0u, 16); __builtin_memcpy(&ap1, &a1u, 16);               \
        for (int c = 0; c < 2; ++c) {                                                     \
            bf16x8 apc = c ? ap1 : ap0;                                                   \
            bf16x8 bv0 = *(const bf16x8*)&VS[m32 * 72        + ktile * 32 + c * 16 + half * 8]; \
            bf16x8 bv1 = *(const bf16x8*)&VS[(32 + m32) * 72 + ktile * 32 + c * 16 + half * 8]; \
            o0 = __builtin_amdgcn_mfma_f32_32x32x16_bf16(apc, bv0, o0, 0, 0, 0);          \
            o1 = __builtin_amdgcn_mfma_f32_32x32x16_bf16(apc, bv1, o1, 0, 0, 0);          \
        }                                                                                 \
    }

    bf16x8 kpA, kpB, vpA, vpB;
    LOADT(0)
    STORET(0)
    __syncthreads();

    for (int kt = 0; kt < 2048; kt += 128) {
        LOADT(kt + 64)                       // prefetch overlaps compute below
        ATTN_STEP(Ks[0], Vs[0])              // tile kt
        STORET(1)
        __syncthreads();
        const bool more = (kt + 128) < 2048;
        if (more) { LOADT(kt + 128) }
        ATTN_STEP(Ks[1], Vs[1])              // tile kt+64
        if (more) {
            STORET(0)
            __syncthreads();
        }
    }
#undef LOADT
#undef STORET
#undef ATTN_STEP

    // rowsum redistribute: lane l holds partial for qrow = l&31
    float fl = ps0 + ps1;
    fl += __shfl_xor(fl, 32, 64);
    for (int r = 0; r < 16; ++r) {
        int m = (r & 3) + 8 * (r >> 2) + 4 * half;
        float inv = 1.0f / __shfl(fl, m, 64);
        long dst = (long)(b * 2048 + q0 + m) * 1024 + h * 64;
        attn[dst + m32]      = f2bf(o0[r] * inv);
        attn[dst + 32 + m32] = f2bf(o1[r] * inv);
    }
}

// ---------------------------------------------------------------------------
extern "C" void kernel_launch(void* const* d_in, const int* in_sizes, int n_in,
                              void* d_out, int out_size, void* d_ws, size_t ws_size,
                              hipStream_t stream) {
    const float* x    = (const float*)d_in[0];
    const float* Wqkv = (const float*)d_in[1];
    const float* qbia = (const float*)d_in[2];
    const float* vbia = (const float*)d_in[3];
    const float* sml  = (const float*)d_in[4];
    const float* Wp   = (const float*)d_in[5];
    const float* bp   = (const float*)d_in[6];

    char* ws = (char*)d_ws;
    unsigned short* qkv   = (unsigned short*)ws;                    // [0, 50.33MB)
    unsigned short* Wpb   = (unsigned short*)ws;                    // reuses qkv after attn
    unsigned short* kbuf  = (unsigned short*)(ws + 50331648);       // hosts Wqkvb first
    unsigned short* Wqkvb = kbuf;
    unsigned short* vT    = (unsigned short*)(ws + 67108864);       // hosts xb first
    unsigned short* xb    = vT;
    unsigned short* attn  = (unsigned short*)(ws + 83886080);
    float*          bias3 = (float*)(ws + 100663296);
    float*          out   = (float*)d_out;

    hipLaunchKernelGGL(k_cast_bf16, dim3(4096), dim3(256), 0, stream, x, xb, 1048576);
    hipLaunchKernelGGL(k_cast_bf16, dim3(1536), dim3(256), 0, stream, Wqkv, Wqkvb, 393216);
    hipLaunchKernelGGL(k_build_bias, dim3(12), dim3(256), 0, stream, qbia, vbia, bias3);
    hipLaunchKernelGGL((k_gemm_lds<false, false>), dim3(64, 24), dim3(256), 0, stream,
                       xb, (const void*)Wqkvb, bias3, (void*)qkv, 3072, 1024);
    hipLaunchKernelGGL(k_norm_k, dim3(32768), dim3(256), 0, stream, qkv, kbuf);
    hipLaunchKernelGGL(k_vtrans, dim3(32, 64), dim3(256), 0, stream, qkv, vT);
    hipLaunchKernelGGL(k_attn32, dim3(16, 64), dim3(256), 0, stream, qkv, kbuf, vT, sml, attn);
    hipLaunchKernelGGL(k_cast_bf16, dim3(512), dim3(256), 0, stream, Wp, Wpb, 131072);
    hipLaunchKernelGGL((k_gemm_lds<false, true>), dim3(64, 8), dim3(256), 0, stream,
                       attn, (const void*)Wpb, bp, (void*)out, 1024, 1024);
}

// Round 7
// 298.979 us; speedup vs baseline: 1.7703x; 1.0764x over previous
//
#include <hip/hip_runtime.h>
#include <hip/hip_bf16.h>

// Problem: B=4, L=2048, C=1024, H=16, D=64, M=B*L=8192. I/O f32.
// Internal: bf16 MFMA, f32 accumulate. Verified absmax 9.8e-4 (thr 4.04e-3).
// R7: ones-MFMA rowsum back (VALU-bound now), truncation pack, 9->5 kernels
//     (fused casts+bias; fused k-norm+v-transpose).

typedef __attribute__((ext_vector_type(8))) short bf16x8;
typedef __attribute__((ext_vector_type(4))) float f32x4;
typedef __attribute__((ext_vector_type(16))) float f32x16;

#define MAXLOG 4.60517018598809f   // ln(100)
#define LOG2E  1.4426950408889634f

__device__ __forceinline__ float bf2f(unsigned short u) {
    union { unsigned int i; float f; } v; v.i = ((unsigned int)u) << 16; return v.f;
}
__device__ __forceinline__ unsigned short f2bf(float f) {
    union { float f; unsigned int i; } v; v.f = f;
    unsigned int x = v.i;
    return (unsigned short)((x + 0x7FFFu + ((x >> 16) & 1u)) >> 16);  // RNE
}
__device__ __forceinline__ unsigned fbits(float f) {
    union { float f; unsigned u; } v; v.f = f; return v.u;
}
__device__ __forceinline__ bf16x8 pack8(const float* __restrict__ p) {
    float4 a = *(const float4*)p;
    float4 b = *(const float4*)(p + 4);
    bf16x8 r;
    r[0] = (short)f2bf(a.x); r[1] = (short)f2bf(a.y);
    r[2] = (short)f2bf(a.z); r[3] = (short)f2bf(a.w);
    r[4] = (short)f2bf(b.x); r[5] = (short)f2bf(b.y);
    r[6] = (short)f2bf(b.z); r[7] = (short)f2bf(b.w);
    return r;
}
__device__ __forceinline__ void gload_lds16(const void* g, void* l) {
    __builtin_amdgcn_global_load_lds((const __attribute__((address_space(1))) void*)g,
                                     (__attribute__((address_space(3))) void*)l, 16, 0, 0);
}

// ---------------------------------------- fused prep: casts + bias (1 kernel)
// regions (vec8 idx): [0,1048576) x->xb ; [1048576,1441792) Wqkv->Wqkvb ;
// [1441792,1572864) Wp->Wpb ; [1572864,1573248) bias3 (8 scalars each)
__global__ __launch_bounds__(256) void k_prep(
    const float* __restrict__ x, const float* __restrict__ Wqkv,
    const float* __restrict__ Wp, const float* __restrict__ qbia,
    const float* __restrict__ vbia,
    unsigned short* __restrict__ xb, unsigned short* __restrict__ Wqkvb,
    unsigned short* __restrict__ Wpb, float* __restrict__ bias3)
{
    int i = blockIdx.x * 256 + threadIdx.x;
    if (i < 1048576) {
        *(bf16x8*)&xb[(long)i * 8] = pack8(&x[(long)i * 8]);
    } else if (i < 1441792) {
        int j = i - 1048576;
        *(bf16x8*)&Wqkvb[(long)j * 8] = pack8(&Wqkv[(long)j * 8]);
    } else if (i < 1572864) {
        int j = i - 1441792;
        *(bf16x8*)&Wpb[(long)j * 8] = pack8(&Wp[(long)j * 8]);
    } else if (i < 1573248) {
        int j = (i - 1572864) * 8;
        for (int u = 0; u < 8; ++u) {
            int n = j + u;
            float v = 0.0f;
            if (n < 1024) v = qbia[n];
            else if (n >= 2048) v = vbia[n - 2048];
            bias3[n] = v;
        }
    }
}

// --------------------------------------- GEMM, B^T input, global_load_lds staging
template<bool OUT_F32>
__global__ __launch_bounds__(256) void k_gemm_lds(
    const unsigned short* __restrict__ A, const unsigned short* __restrict__ Bh,
    const float* __restrict__ bias, void* __restrict__ Cp, int N, int K)
{
    __shared__ unsigned short As[128 * 32];
    __shared__ unsigned short Bs[128 * 32];
    const int t = threadIdx.x, wave = t >> 6, lane = t & 63;
    const int quad = lane >> 4, l16 = lane & 15;
    const int bm = blockIdx.x * 128, bn = blockIdx.y * 128;
    const int wr = (wave >> 1) * 64, wc = (wave & 1) * 64;
    f32x4 acc[4][4] = {};

    const int srow = lane >> 2;
    const int scol = (lane & 3) * 8;
    const int c0 = wave * 2, c1 = wave * 2 + 1;
    const long ga0 = (long)(bm + c0 * 16 + srow) * K + scol;
    const long ga1 = (long)(bm + c1 * 16 + srow) * K + scol;
    const long gb0 = (long)(bn + c0 * 16 + srow) * K + scol;
    const long gb1 = (long)(bn + c1 * 16 + srow) * K + scol;

    for (int kt = 0; kt < K; kt += 32) {
        __syncthreads();
        gload_lds16(&A[ga0 + kt], &As[c0 * 512]);
        gload_lds16(&A[ga1 + kt], &As[c1 * 512]);
        gload_lds16(&Bh[gb0 + kt], &Bs[c0 * 512]);
        gload_lds16(&Bh[gb1 + kt], &Bs[c1 * 512]);
        __syncthreads();
        bf16x8 af[4], bfr[4];
        for (int i = 0; i < 4; ++i)
            af[i] = *(const bf16x8*)&As[(wr + i * 16 + l16) * 32 + quad * 8];
        for (int j = 0; j < 4; ++j)
            bfr[j] = *(const bf16x8*)&Bs[(wc + j * 16 + l16) * 32 + quad * 8];
        for (int i = 0; i < 4; ++i)
            for (int j = 0; j < 4; ++j)
                acc[i][j] = __builtin_amdgcn_mfma_f32_16x16x32_bf16(af[i], bfr[j], acc[i][j], 0, 0, 0);
    }
    for (int j = 0; j < 4; ++j) {
        int gn = bn + wc + j * 16 + l16;
        float bv = bias[gn];
        for (int i = 0; i < 4; ++i) {
            int gm0 = bm + wr + i * 16 + quad * 4;
            for (int r = 0; r < 4; ++r) {
                float val = acc[i][j][r] + bv;
                if (OUT_F32) ((float*)Cp)[(long)(gm0 + r) * N + gn] = val;
                else ((unsigned short*)Cp)[(long)(gm0 + r) * N + gn] = f2bf(val);
            }
        }
    }
}

// ------------------------- fused k L2-normalize + v transpose (one qkv pass)
__global__ __launch_bounds__(256) void k_prep_kv(
    const unsigned short* __restrict__ qkv, unsigned short* __restrict__ kb,
    unsigned short* __restrict__ vT)
{
    __shared__ unsigned short Vsh[64 * 72];
    const int t = threadIdx.x;
    const int bh = blockIdx.y, l0 = blockIdx.x * 64;
    const int h = bh & 15, b = bh >> 4;
    const int ll = t >> 2, c16 = (t & 3) * 16;
    const long rowbase = (long)(b * 2048 + l0 + ll) * 3072;

    // ---- k: 4 lanes per row, 16 elems each; row-norm via 2 shuffles
    {
        bf16x8 k0 = *(const bf16x8*)&qkv[rowbase + 1024 + h * 64 + c16];
        bf16x8 k1 = *(const bf16x8*)&qkv[rowbase + 1024 + h * 64 + c16 + 8];
        float e[16]; float ss = 0.f;
        for (int j = 0; j < 8; ++j) { e[j]     = bf2f((unsigned short)k0[j]); ss += e[j] * e[j]; }
        for (int j = 0; j < 8; ++j) { e[8 + j] = bf2f((unsigned short)k1[j]); ss += e[8 + j] * e[8 + j]; }
        ss += __shfl_xor(ss, 1, 64);
        ss += __shfl_xor(ss, 2, 64);
        float rs = 1.0f / fmaxf(sqrtf(ss), 1e-12f);
        bf16x8 o0, o1;
        for (int j = 0; j < 8; ++j) o0[j] = (short)f2bf(e[j] * rs);
        for (int j = 0; j < 8; ++j) o1[j] = (short)f2bf(e[8 + j] * rs);
        long dst = ((long)bh * 2048 + l0 + ll) * 64 + c16;
        *(bf16x8*)&kb[dst]     = o0;
        *(bf16x8*)&kb[dst + 8] = o1;
    }
    // ---- v: LDS transpose -> [B,H,D,L]
    *(bf16x8*)&Vsh[ll * 72 + c16]     = *(const bf16x8*)&qkv[rowbase + 2048 + h * 64 + c16];
    *(bf16x8*)&Vsh[ll * 72 + c16 + 8] = *(const bf16x8*)&qkv[rowbase + 2048 + h * 64 + c16 + 8];
    __syncthreads();
    const int d = t >> 2, ls = (t & 3) * 16;
    unsigned short tmp[16];
    for (int j = 0; j < 16; ++j) tmp[j] = Vsh[(ls + j) * 72 + d];
    long dst = (long)(bh * 64 + d) * 2048 + l0 + ls;
    *(bf16x8*)&vT[dst]     = *(bf16x8*)&tmp[0];
    *(bf16x8*)&vT[dst + 8] = *(bf16x8*)&tmp[8];
}

// ------------------------------------------------------------ flash attention
// 32x32x16 MFMA, S^T form (R5 key-permutation: P stays in registers).
// R7: rowsum via ones-MFMA (VALU-bound; MFMA pipe has headroom), truncation
// pack (R5-verified), double-buffered K/V LDS with register prefetch.
__global__ __launch_bounds__(256, 4) void k_attn32(
    const unsigned short* __restrict__ qkv, const unsigned short* __restrict__ kb,
    const unsigned short* __restrict__ vT, const float* __restrict__ sml,
    unsigned short* __restrict__ attn)
{
    __shared__ unsigned short Ks[2][64 * 72];
    __shared__ unsigned short Vs[2][64 * 72];
    const int t = threadIdx.x, wave = t >> 6, lane = t & 63;
    const int m32 = lane & 31, half = lane >> 5;
    const int bh = blockIdx.y, h = bh & 15, b = bh >> 4;
    const int q0 = blockIdx.x * 128 + wave * 32;
    const float scale = __expf(fminf(sml[h], MAXLOG));
    const float c2 = scale * LOG2E;

    // permuted physical key row for the S^T A-frag (swap quads 1<->2, 5<->6)
    const int qd = m32 >> 2, lo = qd & 3;
    const int prow = ((((lo == 1) || (lo == 2)) ? (qd ^ 3) : qd) << 2) | (m32 & 3);

    // fused q load + L2-normalize + scale (B-frag layout)
    bf16x8 aq[4];
    {
        long base = (long)(b * 2048 + q0 + m32) * 3072 + h * 64;
        float e[32]; float ss = 0.f;
        for (int f = 0; f < 4; ++f) {
            aq[f] = *(const bf16x8*)&qkv[base + f * 16 + half * 8];
            for (int j = 0; j < 8; ++j) { float x = bf2f((unsigned short)aq[f][j]); e[f * 8 + j] = x; ss += x * x; }
        }
        ss += __shfl_xor(ss, 32, 64);
        float rs = scale / fmaxf(sqrtf(ss), 1e-12f);
        for (int f = 0; f < 4; ++f)
            for (int j = 0; j < 8; ++j) aq[f][j] = (short)f2bf(e[f * 8 + j] * rs);
    }

    f32x16 o0 = {}, o1 = {}, lacc = {};
    bf16x8 ones; for (int i = 0; i < 8; ++i) ones[i] = (short)0x3F80;
    const int sr = t >> 2, sc = (t & 3) * 16;
    const long kbase = (long)bh * 2048 * 64;
    const long vbase = (long)bh * 64 * 2048;

#define LOADT(kt) \
    kpA = *(const bf16x8*)&kb[kbase + (long)((kt) + sr) * 64 + sc];      \
    kpB = *(const bf16x8*)&kb[kbase + (long)((kt) + sr) * 64 + sc + 8];  \
    vpA = *(const bf16x8*)&vT[vbase + (long)sr * 2048 + (kt) + sc];      \
    vpB = *(const bf16x8*)&vT[vbase + (long)sr * 2048 + (kt) + sc + 8];

#define STORET(buf) \
    *(bf16x8*)&Ks[buf][sr * 72 + sc]     = kpA;  \
    *(bf16x8*)&Ks[buf][sr * 72 + sc + 8] = kpB;  \
    *(bf16x8*)&Vs[buf][sr * 72 + sc]     = vpA;  \
    *(bf16x8*)&Vs[buf][sr * 72 + sc + 8] = vpB;

#define ATTN_STEP(KS, VS) \
    for (int ktile = 0; ktile < 2; ++ktile) {                                             \
        f32x16 s = {};                                                                    \
        for (int f = 0; f < 4; ++f) {                                                     \
            bf16x8 bk = *(const bf16x8*)&KS[(ktile * 32 + prow) * 72 + f * 16 + half * 8];\
            s = __builtin_amdgcn_mfma_f32_32x32x16_bf16(bk, aq[f], s, 0, 0, 0);           \
        }                                                                                 \
        unsigned pu[16];                                                                  \
        for (int j = 0; j < 8; ++j) {                                                     \
            pu[j]     = fbits(__builtin_amdgcn_exp2f(s[j]     * LOG2E - c2));             \
            pu[8 + j] = fbits(__builtin_amdgcn_exp2f(s[8 + j] * LOG2E - c2));             \
        }                                                                                 \
        uint4 a0u, a1u;                                                                   \
        a0u.x = __builtin_amdgcn_perm(pu[1],  pu[0],  0x07060302u);                       \
        a0u.y = __builtin_amdgcn_perm(pu[3],  pu[2],  0x07060302u);                       \
        a0u.z = __builtin_amdgcn_perm(pu[5],  pu[4],  0x07060302u);                       \
        a0u.w = __builtin_amdgcn_perm(pu[7],  pu[6],  0x07060302u);                       \
        a1u.x = __builtin_amdgcn_perm(pu[9],  pu[8],  0x07060302u);                       \
        a1u.y = __builtin_amdgcn_perm(pu[11], pu[10], 0x07060302u);                       \
        a1u.z = __builtin_amdgcn_perm(pu[13], pu[12], 0x07060302u);                       \
        a1u.w = __builtin_amdgcn_perm(pu[15], pu[14], 0x07060302u);                       \
        bf16x8 ap0, ap1;                                                                  \
        __builtin_memcpy(&ap0, &a0u, 16); __builtin_memcpy(&ap1, &a1u, 16);               \
        for (int c = 0; c < 2; ++c) {                                                     \
            bf16x8 apc = c ? ap1 : ap0;                                                   \
            bf16x8 bv0 = *(const bf16x8*)&VS[m32 * 72        + ktile * 32 + c * 16 + half * 8]; \
            bf16x8 bv1 = *(const bf16x8*)&VS[(32 + m32) * 72 + ktile * 32 + c * 16 + half * 8]; \
            o0   = __builtin_amdgcn_mfma_f32_32x32x16_bf16(apc, bv0, o0, 0, 0, 0);        \
            o1   = __builtin_amdgcn_mfma_f32_32x32x16_bf16(apc, bv1, o1, 0, 0, 0);        \
            lacc = __builtin_amdgcn_mfma_f32_32x32x16_bf16(apc, ones, lacc, 0, 0, 0);     \
        }                                                                                 \
    }

    bf16x8 kpA, kpB, vpA, vpB;
    LOADT(0)
    STORET(0)
    __syncthreads();

    for (int kt = 0; kt < 2048; kt += 128) {
        LOADT(kt + 64)                       // prefetch overlaps compute below
        ATTN_STEP(Ks[0], Vs[0])              // tile kt
        STORET(1)
        __syncthreads();
        const bool more = (kt + 128) < 2048;
        if (more) { LOADT(kt + 128) }
        ATTN_STEP(Ks[1], Vs[1])              // tile kt+64
        if (more) {
            STORET(0)
            __syncthreads();
        }
    }
#undef LOADT
#undef STORET
#undef ATTN_STEP

    // epilogue: divide by rowsum (lacc reg r matches o reg r), write attn[B,L,C]
    for (int r = 0; r < 16; ++r) {
        int m = (r & 3) + 8 * (r >> 2) + 4 * half;
        float inv = 1.0f / lacc[r];
        long dst = (long)(b * 2048 + q0 + m) * 1024 + h * 64;
        attn[dst + m32]      = f2bf(o0[r] * inv);
        attn[dst + 32 + m32] = f2bf(o1[r] * inv);
    }
}

// ---------------------------------------------------------------------------
extern "C" void kernel_launch(void* const* d_in, const int* in_sizes, int n_in,
                              void* d_out, int out_size, void* d_ws, size_t ws_size,
                              hipStream_t stream) {
    const float* x    = (const float*)d_in[0];
    const float* Wqkv = (const float*)d_in[1];
    const float* qbia = (const float*)d_in[2];
    const float* vbia = (const float*)d_in[3];
    const float* sml  = (const float*)d_in[4];
    const float* Wp   = (const float*)d_in[5];
    const float* bp   = (const float*)d_in[6];

    char* ws = (char*)d_ws;
    unsigned short* qkv   = (unsigned short*)ws;                    // [0, 50.33MB)
    unsigned short* kbuf  = (unsigned short*)(ws + 50331648);       // hosts Wqkvb first
    unsigned short* Wqkvb = kbuf;
    unsigned short* vT    = (unsigned short*)(ws + 67108864);       // hosts xb first
    unsigned short* xb    = vT;
    unsigned short* attnb = (unsigned short*)(ws + 83886080);
    float*          bias3 = (float*)(ws + 100663296);               // 12KB
    unsigned short* Wpb   = (unsigned short*)(ws + 100679680);      // 2MB
    float*          out   = (float*)d_out;

    hipLaunchKernelGGL(k_prep, dim3(6146), dim3(256), 0, stream,
                       x, Wqkv, Wp, qbia, vbia, xb, Wqkvb, Wpb, bias3);
    hipLaunchKernelGGL((k_gemm_lds<false>), dim3(64, 24), dim3(256), 0, stream,
                       xb, Wqkvb, bias3, (void*)qkv, 3072, 1024);
    hipLaunchKernelGGL(k_prep_kv, dim3(32, 64), dim3(256), 0, stream, qkv, kbuf, vT);
    hipLaunchKernelGGL(k_attn32, dim3(16, 64), dim3(256), 0, stream, qkv, kbuf, vT, sml, attnb);
    hipLaunchKernelGGL((k_gemm_lds<true>), dim3(64, 8), dim3(256), 0, stream,
                       attnb, Wpb, bp, (void*)out, 1024, 1024);
}